// Round 6
// baseline (1440.241 us; speedup 1.0000x reference)
//
#include <hip/hip_runtime.h>

// LSTM BS=512, T=2048, IN=64, HS=128.  Single fused persistent kernel:
// 256 blocks x 2 batch rows, 8 waves. Every CH=64 steps, a dense chunk-GEMM
// computes Z = x@W + bias for the next 64 timesteps into LDS (scan-native
// layout); the 64 scan steps then do only K=128 (U*h) MFMAs with acc
// initialized from a register-prefetched Z chunk. Scan MFMAs are kt-outer
// (4 independent acc chains) to avoid dependent-MFMA stalls.

#define T_STEPS 2048
#define IN_DIM 64
#define HS 128
#define NG 512
#define ROWS 2
#define NBLK 256
#define NTHR 512
#define HSTR 144
#define CH 64
#define NCH (T_STEPS / CH)

typedef float f32x4 __attribute__((ext_vector_type(4)));
typedef short s16x8 __attribute__((ext_vector_type(8)));

__device__ __forceinline__ unsigned short f2bf(float f) {
  unsigned u = __float_as_uint(f);
  return (unsigned short)((u + 0x7fffu + ((u >> 16) & 1u)) >> 16);  // RNE
}
__device__ __forceinline__ float bf2f(unsigned short s) {
  return __int_as_float(((int)s) << 16);
}
__device__ __forceinline__ float rcpf(float x) { return __builtin_amdgcn_rcpf(x); }
__device__ __forceinline__ float sigm(float x) { return rcpf(1.0f + __expf(-x)); }
__device__ __forceinline__ float tanhfast(float x) {
  return 1.0f - 2.0f * rcpf(__expf(2.0f * x) + 1.0f);  // exact at +-inf
}

__global__ __launch_bounds__(NTHR, 1)
void lstm_fused(const float* __restrict__ X, const float* __restrict__ W,
                const float* __restrict__ U, const float* __restrict__ B,
                const float* __restrict__ LW, const float* __restrict__ LB,
                float* __restrict__ OUT) {
  // Zc cell (tl, col): 8 shorts = [r0:n0..n3 | r1:n0..n3], 16B aligned
  __shared__ __align__(16) short Zc[CH * 128 * 8];     // 128 KB
  __shared__ __align__(16) short Hb[2][ROWS * HSTR];   // h double buffer
  __shared__ float Ys[256];
  __shared__ float Ps[8];

  const int tid  = threadIdx.x;
  const int lane = tid & 63;
  const int w    = tid >> 6;
  const int blk  = blockIdx.x;
  const int lrow = lane & 15;
  const int lg   = lane >> 4;
  const int col8 = (w * 16 + lrow) * 8;   // Zc column offset (shorts)

  // ---- persistent weight fragments: wave w owns col p = n*128 + 16w + lrow
  // of gate n (n-tile n).  B-frag: B[k][p], k = kt*32 + 8*lg + j.
  s16x8 bfrU[4][4];   // K=128 (U)
  s16x8 bfrW[4][2];   // K=64  (W)
  float biasg[4];
#pragma unroll
  for (int n = 0; n < 4; ++n) {
    const int p = n * HS + w * 16 + lrow;
#pragma unroll
    for (int kt = 0; kt < 4; ++kt)
#pragma unroll
      for (int j = 0; j < 8; ++j)
        bfrU[n][kt][j] = (short)f2bf(U[(kt * 32 + (lg << 3) + j) * NG + p]);
#pragma unroll
    for (int kt = 0; kt < 2; ++kt)
#pragma unroll
      for (int j = 0; j < 8; ++j)
        bfrW[n][kt][j] = (short)f2bf(W[(kt * 32 + (lg << 3) + j) * NG + p]);
    biasg[n] = B[p];
  }

  // ---- chunk-GEMM A-tile source: lane -> batch row (lrow&1), t-row (lrow>>1)
  const float* xbA = X + ((long)(blk * ROWS + (lrow & 1)) * T_STEPS + (lrow >> 1)) * IN_DIM + (lg << 3);

  // prefetch chunk 0, m-tile 0
  f32x4 qp0 = *(const f32x4*)(xbA);
  f32x4 qp1 = *(const f32x4*)(xbA + 4);
  f32x4 qp2 = *(const f32x4*)(xbA + 32);
  f32x4 qp3 = *(const f32x4*)(xbA + 36);

  s16x8 afr[4];
  const s16x8 zer = {0, 0, 0, 0, 0, 0, 0, 0};
#pragma unroll
  for (int kt = 0; kt < 4; ++kt) afr[kt] = zer;  // h(0) = 0

  float creg = 0.f, hreg = 0.f;

#pragma unroll 1
  for (int c = 0; c < NCH; ++c) {
    // ================= chunk GEMM: Zc = x@W + bias for t in [64c, 64c+64) ==
    {
      const float* xc = xbA + (long)c * CH * IN_DIM;
      f32x4 q0 = qp0, q1 = qp1, q2 = qp2, q3 = qp3;
#pragma unroll
      for (int mt = 0; mt < 8; ++mt) {
        f32x4 n0, n1, n2, n3;
        if (mt < 7) {
          const float* p = xc + (mt + 1) * 8 * IN_DIM;
          n0 = *(const f32x4*)(p);      n1 = *(const f32x4*)(p + 4);
          n2 = *(const f32x4*)(p + 32); n3 = *(const f32x4*)(p + 36);
        }
        s16x8 a0, a1;
#pragma unroll
        for (int j = 0; j < 4; ++j) {
          a0[j] = (short)f2bf(q0[j]); a0[4 + j] = (short)f2bf(q1[j]);
          a1[j] = (short)f2bf(q2[j]); a1[4 + j] = (short)f2bf(q3[j]);
        }
        f32x4 ac[4];
#pragma unroll
        for (int n = 0; n < 4; ++n) {
          ac[n][0] = biasg[n]; ac[n][1] = biasg[n];
          ac[n][2] = biasg[n]; ac[n][3] = biasg[n];
        }
#pragma unroll
        for (int n = 0; n < 4; ++n)
          ac[n] = __builtin_amdgcn_mfma_f32_16x16x32_bf16(a0, bfrW[n][0], ac[n], 0, 0, 0);
#pragma unroll
        for (int n = 0; n < 4; ++n)
          ac[n] = __builtin_amdgcn_mfma_f32_16x16x32_bf16(a1, bfrW[n][1], ac[n], 0, 0, 0);

        // D row d=4lg+rr -> m-row 16mt+d -> (tl = 8mt+2lg+(rr>>1), r = rr&1)
        s16x8 z0, z1;
#pragma unroll
        for (int n = 0; n < 4; ++n) {
          z0[n] = (short)f2bf(ac[n][0]); z0[4 + n] = (short)f2bf(ac[n][1]);
          z1[n] = (short)f2bf(ac[n][2]); z1[4 + n] = (short)f2bf(ac[n][3]);
        }
        const int tl0 = mt * 8 + 2 * lg;
        *(s16x8*)&Zc[tl0 * 1024 + col8]       = z0;
        *(s16x8*)&Zc[(tl0 + 1) * 1024 + col8] = z1;
        q0 = n0; q1 = n1; q2 = n2; q3 = n3;
      }
      // prefetch next chunk's m-tile 0 (clamped; lands during scan steps)
      const float* pn = xbA + (long)((c + 1 < NCH) ? c + 1 : c) * CH * IN_DIM;
      qp0 = *(const f32x4*)(pn);      qp1 = *(const f32x4*)(pn + 4);
      qp2 = *(const f32x4*)(pn + 32); qp3 = *(const f32x4*)(pn + 36);
    }
    __syncthreads();

    // Z for tl=0 of this chunk
    s16x8 zreg = *(const s16x8*)&Zc[col8];

    // ================= 64 scan steps =======================================
#pragma unroll 1
    for (int tl = 0; tl < CH; ++tl) {
      const int t = (c << 6) + tl;

      f32x4 acc[4];
#pragma unroll
      for (int n = 0; n < 4; ++n) {
        acc[n][0] = bf2f((unsigned short)zreg[n]);
        acc[n][1] = bf2f((unsigned short)zreg[4 + n]);
        acc[n][2] = 0.f; acc[n][3] = 0.f;
      }

      // kt-outer: 4 independent acc chains, no dependent-MFMA stalls.
      // n order {0,2,1,3}: i,g accs retire first.
#pragma unroll
      for (int kt = 0; kt < 4; ++kt) {
        acc[0] = __builtin_amdgcn_mfma_f32_16x16x32_bf16(afr[kt], bfrU[0][kt], acc[0], 0, 0, 0);
        acc[2] = __builtin_amdgcn_mfma_f32_16x16x32_bf16(afr[kt], bfrU[2][kt], acc[2], 0, 0, 0);
        acc[1] = __builtin_amdgcn_mfma_f32_16x16x32_bf16(afr[kt], bfrU[1][kt], acc[1], 0, 0, 0);
        acc[3] = __builtin_amdgcn_mfma_f32_16x16x32_bf16(afr[kt], bfrU[3][kt], acc[3], 0, 0, 0);
      }

      // i,g first (their accs finish first), f,o while i*g computes
      const float s0 = __int_as_float(
          __builtin_amdgcn_ds_swizzle(__float_as_int(acc[0][1]), 0x401F));
      const float s2 = __int_as_float(
          __builtin_amdgcn_ds_swizzle(__float_as_int(acc[2][1]), 0x401F));
      const float v0 = (lane & 16) ? s0 : acc[0][0];
      const float v2 = (lane & 16) ? s2 : acc[2][0];
      const float iv = sigm(v0), gv = tanhfast(v2);
      const float pg = iv * gv;
      const float s1 = __int_as_float(
          __builtin_amdgcn_ds_swizzle(__float_as_int(acc[1][1]), 0x401F));
      const float s3 = __int_as_float(
          __builtin_amdgcn_ds_swizzle(__float_as_int(acc[3][1]), 0x401F));
      const float v1 = (lane & 16) ? s1 : acc[1][0];
      const float v3 = (lane & 16) ? s3 : acc[3][0];
      const float fv = sigm(v1), ov = sigm(v3);
      creg = fv * creg + pg;
      hreg = ov * tanhfast(creg);

      if (lane < 32) {
        const int col = w * 16 + lrow;
        const int r   = lg & 1;
        if (t < T_STEPS - 1) {
          Hb[(t + 1) & 1][r * HSTR + col] = (short)f2bf(hreg);
        } else {
          const int row = blk * ROWS + r;
          OUT[512 + row * HS + col]   = hreg;   // h_t
          OUT[66048 + row * HS + col] = creg;   // c_t
          Ys[r * HS + col] = LW[col] * hreg;    // y partials
        }
      }
      __syncthreads();

      if (t < T_STEPS - 1 && lrow < ROWS) {     // h fragments for step t+1
        const short* hb = &Hb[(t + 1) & 1][lrow * HSTR];
        afr[0] = *(const s16x8*)&hb[(lg << 3)];
        afr[1] = *(const s16x8*)&hb[32 + (lg << 3)];
        afr[2] = *(const s16x8*)&hb[64 + (lg << 3)];
        afr[3] = *(const s16x8*)&hb[96 + (lg << 3)];
      }
      if (tl < CH - 1)                          // Z for step t+1 (reg prefetch)
        zreg = *(const s16x8*)&Zc[(tl + 1) * 1024 + col8];
    }
  }

  // ---- y = h @ linear_w.T + b ----
  if (tid < 8) {
    const int r = tid >> 2, seg = tid & 3;
    float s = 0.f;
#pragma unroll 8
    for (int j = 0; j < 32; ++j) s += Ys[r * 128 + seg * 32 + j];
    Ps[tid] = s;
  }
  __syncthreads();
  if (tid < ROWS) {
    OUT[blk * ROWS + tid] = LB[0] + Ps[tid * 4] + Ps[tid * 4 + 1]
                                  + Ps[tid * 4 + 2] + Ps[tid * 4 + 3];
  }
}

extern "C" void kernel_launch(void* const* d_in, const int* in_sizes, int n_in,
                              void* d_out, int out_size, void* d_ws, size_t ws_size,
                              hipStream_t stream) {
  const float* X  = (const float*)d_in[0];
  const float* W  = (const float*)d_in[1];
  const float* U  = (const float*)d_in[2];
  const float* B  = (const float*)d_in[3];
  const float* LW = (const float*)d_in[4];
  const float* LB = (const float*)d_in[5];
  lstm_fused<<<dim3(NBLK), dim3(NTHR), 0, stream>>>(X, W, U, B, LW, LB, (float*)d_out);
}